// Round 3
// baseline (318.850 us; speedup 1.0000x reference)
//
#include <hip/hip_runtime.h>

#define NB 256
#define NT 512
#define NI 64
#define NH 256
#define NO 16

typedef __attribute__((ext_vector_type(8))) short short8;
typedef __attribute__((ext_vector_type(8))) __bf16 bf16x8;
typedef __attribute__((ext_vector_type(4))) float f32x4;

__device__ __forceinline__ unsigned short f2bf(float f) {
  unsigned u = __builtin_bit_cast(unsigned, f);
  u += 0x7fffu + ((u >> 16) & 1u);          // round-to-nearest-even
  return (unsigned short)(u >> 16);
}

__device__ __forceinline__ f32x4 mfma16(short8 a, short8 b, f32x4 c) {
  return __builtin_amdgcn_mfma_f32_16x16x32_bf16(
      __builtin_bit_cast(bf16x8, a), __builtin_bit_cast(bf16x8, b), c, 0, 0, 0);
}

__device__ __forceinline__ short8 pack8v(f32x4 lo, f32x4 hi) {
  short8 r;
#pragma unroll
  for (int i = 0; i < 4; ++i) {
    r[i]     = (short)f2bf(lo[i]);
    r[i + 4] = (short)f2bf(hi[i]);
  }
  return r;
}

__device__ __forceinline__ short8 pack8(const float* __restrict__ p) {
  return pack8v(*reinterpret_cast<const f32x4*>(p),
                *reinterpret_cast<const f32x4*>(p + 4));
}

// LDS-only barrier: drain our DS ops, sync; global stores/loads stay in flight.
__device__ __forceinline__ void step_barrier() {
  asm volatile("s_waitcnt lgkmcnt(0)" ::: "memory");
  __builtin_amdgcn_s_barrier();
  asm volatile("" ::: "memory");
}

// One block per batch (256 blocks -> 1 per CU). 256 threads = 4 waves, 1/SIMD.
// Wave w owns hidden columns [w*64, w*64+64) as four 16-wide j-tiles.
// Lane l (global within wave) owns hidden unit j = w*64 + l.
__global__ __launch_bounds__(256, 1)
void rnn_fused(const float* __restrict__ x,  const float* __restrict__ Wi,
               const float* __restrict__ bi, const float* __restrict__ Wh,
               const float* __restrict__ bh, const float* __restrict__ Wo,
               const float* __restrict__ bo, const float* __restrict__ h0,
               float* __restrict__ dout)
{
  const int b   = blockIdx.x;
  const int tid = threadIdx.x;
  const int w   = tid >> 6;   // wave 0..3
  const int l   = tid & 63;   // lane
  const int lg  = l >> 4;     // 16-lane group 0..3
  const int ll  = l & 15;     // row/col within tile

  __shared__ __align__(16) unsigned short rnnwin[16 * NH]; // 8 KB, XOR-swizzled rows
  __shared__ __align__(16) float          xi_win[16 * NH]; // 16 KB

  float* outp = dout;                              // [B,T,O]
  float* hidp = dout + (size_t)NB * NT * NO;       // [B,H]
  float* rnnp = hidp + (size_t)NB * NH;            // [B,T,H]

  // ---- persistent W_h2h B-fragments: B[k][n]; lane holds n=ll, k=kt*32+lg*8+e
  short8 whf[4][8];
#pragma unroll
  for (int jt = 0; jt < 4; ++jt) {
    const int j = w * 64 + jt * 16 + ll;
#pragma unroll
    for (int kt = 0; kt < 8; ++kt)
      whf[jt][kt] = pack8(Wh + (size_t)j * NH + kt * 32 + lg * 8);
  }
  // ---- persistent W_i2h B-fragments ----
  short8 wif[4][2];
#pragma unroll
  for (int jt = 0; jt < 4; ++jt) {
    const int j = w * 64 + jt * 16 + ll;
#pragma unroll
    for (int kt = 0; kt < 2; ++kt)
      wif[jt][kt] = pack8(Wi + (size_t)j * NI + kt * 32 + lg * 8);
  }
  float breg[4];
#pragma unroll
  for (int jt = 0; jt < 4; ++jt)
    breg[jt] = bi[w * 64 + jt * 16 + ll] + bh[w * 64 + jt * 16 + ll];
  const float bout = bo[ll];

  // hidden state: each lane owns h[w*64+l] in fp32; bf16 broadcast A-frags
  float h_reg = h0[w * 64 + l];
  short8 haf[8];
#pragma unroll
  for (int kt = 0; kt < 8; ++kt) haf[kt] = pack8(h0 + kt * 32 + lg * 8);

  // ---- x prefetch (one window ahead), 16 floats/thread ----
  f32x4 xpre[4];
  {
    const float* xp = x + (size_t)b * NT * NI + (size_t)ll * NI + lg * 8;
    xpre[0] = *reinterpret_cast<const f32x4*>(xp);
    xpre[1] = *reinterpret_cast<const f32x4*>(xp + 4);
    xpre[2] = *reinterpret_cast<const f32x4*>(xp + 32);
    xpre[3] = *reinterpret_cast<const f32x4*>(xp + 36);
  }

  const f32x4 cz = {0.f, 0.f, 0.f, 0.f};

#pragma unroll 1
  for (int t = 0; t < NT; ++t) {
    const int trow = t & 15;
    if (trow == 0) {
      // ---- output projection of completed previous window (wave 0 only) ----
      if (t > 0 && w == 0) {
        f32x4 oacc = cz;
#pragma unroll
        for (int kt = 0; kt < 8; ++kt) {
          const char* ap = (const char*)rnnwin + ll * 512 +
                           ((kt * 64 + lg * 16) ^ (ll << 4));
          short8 af = *reinterpret_cast<const short8*>(ap);
          short8 bf = pack8(Wo + (size_t)ll * NH + kt * 32 + lg * 8);
          oacc = mfma16(af, bf, oacc);
        }
        const int t0 = t - 16;
#pragma unroll
        for (int r = 0; r < 4; ++r)
          outp[((size_t)b * NT + t0 + lg * 4 + r) * NO + ll] = oacc[r] + bout;
      }
      // ---- i2h GEMM for window [t, t+16) from prefetched registers ----
      {
        short8 xf0 = pack8v(xpre[0], xpre[1]);
        short8 xf1 = pack8v(xpre[2], xpre[3]);
#pragma unroll
        for (int jt = 0; jt < 4; ++jt) {
          f32x4 acc = mfma16(xf0, wif[jt][0], cz);
          acc = mfma16(xf1, wif[jt][1], acc);
#pragma unroll
          for (int r = 0; r < 4; ++r)
            xi_win[(lg * 4 + r) * NH + w * 64 + jt * 16 + ll] = acc[r] + breg[jt];
        }
      }
      if (t + 16 < NT) {
        const float* xp = x + (size_t)b * NT * NI + (size_t)(t + 16 + ll) * NI + lg * 8;
        xpre[0] = *reinterpret_cast<const f32x4*>(xp);
        xpre[1] = *reinterpret_cast<const f32x4*>(xp + 4);
        xpre[2] = *reinterpret_cast<const f32x4*>(xp + 32);
        xpre[3] = *reinterpret_cast<const f32x4*>(xp + 36);
      }
      step_barrier();
    }

    // ---- h+xi folded into MFMA C-in element 0 (row lg*4, col ll — the exact
    //      element this lane reads back from its selected tile jt==lg) ----
    const float xi = xi_win[trow * NH + w * 64 + l];
    f32x4 cin = cz;
    cin[0] = h_reg + xi;

    // ---- h2h matvec: 8 independent 4-deep chains (4 j-tiles x 2 k-halves) --
    f32x4 aA[4], aB[4];
#pragma unroll
    for (int jt = 0; jt < 4; ++jt) aA[jt] = mfma16(haf[0], whf[jt][0], cin);
#pragma unroll
    for (int jt = 0; jt < 4; ++jt) aB[jt] = mfma16(haf[4], whf[jt][4], cz);
#pragma unroll
    for (int kt = 1; kt < 4; ++kt) {
#pragma unroll
      for (int jt = 0; jt < 4; ++jt) {
        aA[jt] = mfma16(haf[kt],     whf[jt][kt],     aA[jt]);
        aB[jt] = mfma16(haf[kt + 4], whf[jt][kt + 4], aB[jt]);
      }
    }
    const float s0 = aA[0][0] + aB[0][0];
    const float s1 = aA[1][0] + aB[1][0];
    const float s2 = aA[2][0] + aB[2][0];
    const float s3 = aA[3][0] + aB[3][0];
    const float sv = (lg < 2) ? ((lg == 0) ? s0 : s1) : ((lg == 2) ? s2 : s3);
    const float a  = fminf(fmaxf(sv, 0.f), 1.f);
    h_reg = a;

    // one bf16 LDS write per lane (own j), XOR-swizzled row
    {
      const int byte = trow * 512 + ((2 * (w * 64 + l)) ^ (trow << 4));
      rnnwin[byte >> 1] = f2bf(a);
    }
    // coalesced rnn_out store (stays in flight; barrier never drains vmcnt)
    rnnp[((size_t)b * NT + t) * NH + w * 64 + l] = a;

    step_barrier();

    // broadcast A-fragments of h_t for the next step
#pragma unroll
    for (int kt = 0; kt < 8; ++kt) {
      const char* ap = (const char*)rnnwin + trow * 512 +
                       ((kt * 64 + lg * 16) ^ (trow << 4));
      haf[kt] = *reinterpret_cast<const short8*>(ap);
    }
  }

  // ---- final window's output projection ----
  if (w == 0) {
    f32x4 oacc = cz;
#pragma unroll
    for (int kt = 0; kt < 8; ++kt) {
      const char* ap = (const char*)rnnwin + ll * 512 +
                       ((kt * 64 + lg * 16) ^ (ll << 4));
      short8 af = *reinterpret_cast<const short8*>(ap);
      short8 bf = pack8(Wo + (size_t)ll * NH + kt * 32 + lg * 8);
      oacc = mfma16(af, bf, oacc);
    }
#pragma unroll
    for (int r = 0; r < 4; ++r)
      outp[((size_t)b * NT + (NT - 16) + lg * 4 + r) * NO + ll] = oacc[r] + bout;
  }
  // ---- hidden = h after T steps ----
  hidp[(size_t)b * NH + w * 64 + l] = h_reg;
}

extern "C" void kernel_launch(void* const* d_in, const int* in_sizes, int n_in,
                              void* d_out, int out_size, void* d_ws, size_t ws_size,
                              hipStream_t stream) {
  const float* x  = (const float*)d_in[0];
  const float* Wi = (const float*)d_in[1];
  const float* bi = (const float*)d_in[2];
  const float* Wh = (const float*)d_in[3];
  const float* bh = (const float*)d_in[4];
  const float* Wo = (const float*)d_in[5];
  const float* bo = (const float*)d_in[6];
  const float* h0 = (const float*)d_in[7];
  rnn_fused<<<dim3(NB), dim3(256), 0, stream>>>(x, Wi, bi, Wh, bh, Wo, bo, h0,
                                                (float*)d_out);
}